// Round 8
// baseline (381.912 us; speedup 1.0000x reference)
//
#include <hip/hip_runtime.h>
#include <stdint.h>

#define SS 4096     // tokens per batch (H*W)
#define CC 64       // channels
#define BB 16       // batch

typedef unsigned short u16;
typedef __attribute__((ext_vector_type(8))) __bf16 bf16x8;
typedef __attribute__((ext_vector_type(8))) short short8;
typedef __attribute__((ext_vector_type(4))) short s16x4;
typedef __attribute__((ext_vector_type(4))) float f32x4;

// pack two f32 -> two bf16 in one u32 (low = a, high = b), round-half-up
__device__ __forceinline__ uint32_t pkbf(float a, float b) {
    uint32_t ua = __float_as_uint(a) + 0x8000u;
    uint32_t ub = __float_as_uint(b) + 0x8000u;
    return __builtin_amdgcn_perm(ub, ua, 0x07060302u);
}

// hardware packed f32x2 -> bf16x2 (RNE), low = a, high = b
__device__ __forceinline__ uint32_t cvtpk(float a, float b) {
    uint32_t r;
    asm("v_cvt_pk_bf16_f32 %0, %1, %2" : "=v"(r) : "v"(a), "v"(b));
    return r;
}

// load 8 consecutive fp32 -> bf16x8 fragment (L2-hot, once/block)
__device__ __forceinline__ bf16x8 ldw8(const float* p) {
    f32x4 lo = *(const f32x4*)(p);
    f32x4 hi = *(const f32x4*)(p + 4);
    union { uint32_t u[4]; bf16x8 v; } r;
    r.u[0] = pkbf(lo[0], lo[1]);
    r.u[1] = pkbf(lo[2], lo[3]);
    r.u[2] = pkbf(hi[0], hi[1]);
    r.u[3] = pkbf(hi[2], hi[3]);
    return r.v;
}

// ---------------------------------------------------------------------------
// Kernel A: QKV projection — R2-verified version, unchanged.
// ---------------------------------------------------------------------------
__global__ __launch_bounds__(256, 4) void qkv_kernel(
    const float* __restrict__ x,
    const float* __restrict__ qw, const float* __restrict__ qb,
    const float* __restrict__ kw, const float* __restrict__ kb,
    const float* __restrict__ vw, const float* __restrict__ vb,
    u16* __restrict__ Q, u16* __restrict__ K, u16* __restrict__ VT)
{
    const int b    = blockIdx.x & 15;          // batch-major for XCD locality
    const int s0   = (blockIdx.x >> 4) << 6;   // 64 s per block
    const int tid  = threadIdx.x;
    const int w    = tid >> 6;
    const int lane = tid & 63;
    const int lq   = lane & 15;
    const int quad = lane >> 4;

    __shared__ u16 wt[3][64 * 72];             // weights bf16 [o][c]
    __shared__ u16 xt[64 * 72];                // x-tile transposed [s][c]; later bounce

    // ---- stage weights bf16 (coalesced 512-B reads, conflict-spread writes) ----
    for (int m = 0; m < 3; ++m) {
        const float* wsrc = (m == 0) ? qw : ((m == 1) ? kw : vw);
#pragma unroll
        for (int i = 0; i < 8; ++i) {
            int p  = tid + (i << 8);           // pair index 0..2047
            int o  = p >> 5;
            int cp = p & 31;
            const float* wp = wsrc + o * 64 + cp * 2;
            ((uint32_t*)&wt[m][o * 72])[cp] = pkbf(wp[0], wp[1]);
        }
    }
    // ---- stage x-tile transposed (reads: 64 consecutive s = 256 B/instr) ----
    {
        const int sl = tid & 63;
        const int g  = tid >> 6;
        const float* xp = x + (size_t)b * CC * SS + s0 + sl;
#pragma unroll
        for (int i = 0; i < 8; ++i) {
            int p = g + (i << 2);              // c-pair 0..31
            float f0 = xp[(size_t)(2 * p) * SS];
            float f1 = xp[(size_t)(2 * p + 1) * SS];
            ((uint32_t*)&xt[sl * 72])[p] = pkbf(f0, f1);
        }
    }
    __syncthreads();

    // A-frags for my 16 s-rows
    bf16x8 a0 = *(const bf16x8*)&xt[(w * 16 + lq) * 72 + quad * 8];
    bf16x8 a1 = *(const bf16x8*)&xt[(w * 16 + lq) * 72 + 32 + quad * 8];
    __syncthreads();                           // xt dead -> reuse as bounce

    u16* bb = xt + w * (16 * 72);              // per-wave bounce

    const float QSCALE = 0.125f * 1.44269504088896340736f;

    for (int m = 0; m < 3; ++m) {
        const float* bsrc = (m == 0) ? qb : ((m == 1) ? kb : vb);
        bf16x8 bfr[2][4];
#pragma unroll
        for (int kc = 0; kc < 2; ++kc)
#pragma unroll
            for (int nt = 0; nt < 4; ++nt)
                bfr[kc][nt] = *(const bf16x8*)&wt[m][(nt * 16 + lq) * 72 + kc * 32 + quad * 8];

        f32x4 acc[4];
#pragma unroll
        for (int nt = 0; nt < 4; ++nt) {
            float bv = bsrc[nt * 16 + lq];
            acc[nt] = (f32x4){bv, bv, bv, bv};
        }
#pragma unroll
        for (int nt = 0; nt < 4; ++nt) {
            acc[nt] = __builtin_amdgcn_mfma_f32_16x16x32_bf16(a0, bfr[0][nt], acc[nt], 0, 0, 0);
            acc[nt] = __builtin_amdgcn_mfma_f32_16x16x32_bf16(a1, bfr[1][nt], acc[nt], 0, 0, 0);
        }

        if (m == 2) {
            // VT[b][c][s]: lane has col c, 4 consecutive s -> 8B store
#pragma unroll
            for (int nt = 0; nt < 4; ++nt) {
                int c = nt * 16 + lq;
                uint2 pv;
                pv.x = pkbf(acc[nt][0], acc[nt][1]);
                pv.y = pkbf(acc[nt][2], acc[nt][3]);
                *(uint2*)(VT + ((size_t)(b * CC + c)) * SS + s0 + w * 16 + quad * 4) = pv;
            }
        } else {
            const float scl = (m == 0) ? QSCALE : 1.0f;
#pragma unroll
            for (int nt = 0; nt < 4; ++nt)
#pragma unroll
                for (int r = 0; r < 4; ++r)
                    bb[(quad * 4 + r) * 72 + nt * 16 + lq] =
                        (u16)((__float_as_uint(acc[nt][r] * scl) + 0x8000u) >> 16);

            const int row = lane >> 2;
            const int ch  = (lane & 3) << 4;
            short8 v0 = *(const short8*)&bb[row * 72 + ch];       // wave-private RAW
            short8 v1 = *(const short8*)&bb[row * 72 + ch + 8];
            u16* dst = ((m == 0) ? Q : K) + ((size_t)(b * SS + s0 + w * 16 + row)) * CC + ch;
            *(short8*)dst = v0;
            *(short8*)(dst + 8) = v1;
        }
    }
}

// ---------------------------------------------------------------------------
// Kernel B: flash attention + fused out-projection.
// V13c: 2x2 wave split (wk = 32-key half, wq = 64-q half; frag ds_reads
// halved vs R2). Main loop identical to R5/R7 (absmax-verified twice).
// Epilogue scratch-free at last: R7's `f32x4* kp = t ? kp1 : kp0` took the
// ADDRESS of register arrays -> stack (WRITE_SIZE 1.9GB). Now the t-loop is
// macro-unrolled with the array NAME substituted (kp0/kp1 used directly);
// no pointers to locals, no runtime array indices anywhere.
// ---------------------------------------------------------------------------
__global__ __launch_bounds__(256, 2) void flash_kernel(
    const u16* __restrict__ Q, const u16* __restrict__ K,
    const u16* __restrict__ Vt, const float* __restrict__ ow,
    const float* __restrict__ ob, float* __restrict__ out)
{
    const int b    = blockIdx.x & 15;          // batch-major: XCD gets 2 batches
    const int q0   = (blockIdx.x >> 4) << 7;   // 128 q per block
    const int tid  = threadIdx.x;
    const int w    = tid >> 6;
    const int lane = tid & 63;
    const int lq   = lane & 15;
    const int quad = lane >> 4;
    const int wk   = w & 1;                    // key-half owner (keys [wk*32, wk*32+32))
    const int wq   = w >> 1;                   // q-half owner  (q [wq*64, wq*64+64))

    __shared__ u16 smem[4 * 4096];             // [K dbuf 2x8KB | V dbuf 2x8KB]; epilogue: f32 red buf
    __shared__ u16 lds_p[8][1024];             // per-(wave,t) O bounce (wave-private)
    __shared__ float lpbuf[8][16];             // per-(wq,qt) l partials

    u16* lds_k = smem;                         // + buf*4096
    u16* lds_v = smem + 2 * 4096;              // + buf*4096

    // Q B-frags: 4 q-subtiles x 2 kc
    bf16x8 qf[4][2];
#pragma unroll
    for (int qt = 0; qt < 4; ++qt) {
        const u16* qp = Q + ((size_t)(b * SS + q0 + wq * 64 + qt * 16 + lq)) * CC + quad * 8;
        qf[qt][0] = *(const bf16x8*)(qp);
        qf[qt][1] = *(const bf16x8*)(qp + 32);
    }

    f32x4 ot[4][4];                            // [qt][ct] partial O^T over wk's keys
#pragma unroll
    for (int qt = 0; qt < 4; ++qt)
#pragma unroll
        for (int ct = 0; ct < 4; ++ct) ot[qt][ct] = (f32x4){0.f, 0.f, 0.f, 0.f};
    float lp[4][4];
#pragma unroll
    for (int qt = 0; qt < 4; ++qt)
#pragma unroll
        for (int r = 0; r < 4; ++r) lp[qt][r] = 0.f;

    const f32x4 ZV = (f32x4){0.f, 0.f, 0.f, 0.f};

    // staging (R2-verbatim): thread covers row srow, K chunks 2a,2a+1; V 4x8B permuted
    const int srow = tid >> 2;
    const int a    = tid & 3;
    const u16* kg = K + ((size_t)(b * SS + srow)) * CC + a * 16;
    const u16* vg = Vt + ((size_t)(b * CC + srow)) * SS + a * 16;
    const int ssw = srow & 7;
    const int sw0 = srow * 64 + ((((a << 1)    ) ^ ssw) << 3);
    const int sw1 = srow * 64 + ((((a << 1) | 1) ^ ssw) << 3);
    const int kcs = (a >> 1) << 2;
    const int us  = (a & 1) << 2;
    const int vw0 = srow * 64 + (((kcs + 0) ^ ssw) << 3) + us;
    const int vw1 = srow * 64 + (((kcs + 1) ^ ssw) << 3) + us;
    const int vw2 = srow * 64 + (((kcs + 2) ^ ssw) << 3) + us;
    const int vw3 = srow * 64 + (((kcs + 3) ^ ssw) << 3) + us;

    {   // prologue: tile 0 -> buf 0
        short8 k0 = *(const short8*)(kg);
        short8 k1 = *(const short8*)(kg + 8);
        union { short8 v; s16x4 h[2]; } v0, v1;
        v0.v = *(const short8*)(vg);
        v1.v = *(const short8*)(vg + 8);
        *(short8*)&lds_k[sw0] = k0;
        *(short8*)&lds_k[sw1] = k1;
        *(s16x4*)&lds_v[vw0] = v0.h[0];
        *(s16x4*)&lds_v[vw1] = v0.h[1];
        *(s16x4*)&lds_v[vw2] = v1.h[0];
        *(s16x4*)&lds_v[vw3] = v1.h[1];
    }

    const int lsw = lq & 7;

    for (int kt = 0; kt < 64; ++kt) {
        __syncthreads();
        const int buf = kt & 1;
        u16* lkb = lds_k + buf * 4096;
        u16* lvb = lds_v + buf * 4096;

        // prefetch tile kt+1 (consumed at end of body)
        const int ktn = (kt + 1) & 63;
        const u16* kgn = kg + (size_t)ktn * (64 * CC);
        const u16* vgn = vg + ktn * 64;
        short8 nk0 = *(const short8*)(kgn);
        short8 nk1 = *(const short8*)(kgn + 8);
        union { short8 v; s16x4 h[2]; } nv0, nv1;
        nv0.v = *(const short8*)(vgn);
        nv1.v = *(const short8*)(vgn + 8);

        // kf: only wk's 32-key half (4 frags)
        bf16x8 kf[2][2];
#pragma unroll
        for (int kc = 0; kc < 2; ++kc)
#pragma unroll
            for (int mt = 0; mt < 2; ++mt)
                kf[kc][mt] = *(const bf16x8*)
                    &lkb[((wk * 2 + mt) * 16 + lq) * 64 + (((kc << 2) + quad) ^ lsw) * 8];

        // vf: only wk's key-chunk (kc = wk), 4 frags
        bf16x8 vf[4];
#pragma unroll
        for (int ct = 0; ct < 4; ++ct)
            vf[ct] = *(const bf16x8*)
                &lvb[(ct * 16 + lq) * 64 + (((wk << 2) + quad) ^ lsw) * 8];

        // per q-subtile: QK -> softmax -> PV (MFMA of qt+1 overlaps VALU of qt)
#pragma unroll
        for (int qt = 0; qt < 4; ++qt) {
            f32x4 s0, s1;
            __builtin_amdgcn_s_setprio(1);
            s0 = __builtin_amdgcn_mfma_f32_16x16x32_bf16(kf[0][0], qf[qt][0], ZV, 0, 0, 0);
            s0 = __builtin_amdgcn_mfma_f32_16x16x32_bf16(kf[1][0], qf[qt][1], s0, 0, 0, 0);
            s1 = __builtin_amdgcn_mfma_f32_16x16x32_bf16(kf[0][1], qf[qt][0], ZV, 0, 0, 0);
            s1 = __builtin_amdgcn_mfma_f32_16x16x32_bf16(kf[1][1], qf[qt][1], s1, 0, 0, 0);
            __builtin_amdgcn_s_setprio(0);

            float p00 = __builtin_amdgcn_exp2f(s0[0]);
            float p01 = __builtin_amdgcn_exp2f(s0[1]);
            float p02 = __builtin_amdgcn_exp2f(s0[2]);
            float p03 = __builtin_amdgcn_exp2f(s0[3]);
            float p10 = __builtin_amdgcn_exp2f(s1[0]);
            float p11 = __builtin_amdgcn_exp2f(s1[1]);
            float p12 = __builtin_amdgcn_exp2f(s1[2]);
            float p13 = __builtin_amdgcn_exp2f(s1[3]);
            lp[qt][0] += p00 + p10;
            lp[qt][1] += p01 + p11;
            lp[qt][2] += p02 + p12;
            lp[qt][3] += p03 + p13;

            union { uint32_t u[4]; bf16x8 v; } pf;
            pf.u[0] = cvtpk(p00, p01);
            pf.u[1] = cvtpk(p02, p03);
            pf.u[2] = cvtpk(p10, p11);
            pf.u[3] = cvtpk(p12, p13);

            __builtin_amdgcn_s_setprio(1);
#pragma unroll
            for (int ct = 0; ct < 4; ++ct)
                ot[qt][ct] = __builtin_amdgcn_mfma_f32_16x16x32_bf16(
                    vf[ct], pf.v, ot[qt][ct], 0, 0, 0);
            __builtin_amdgcn_s_setprio(0);
        }

        // stage prefetched tile into other buffer
        u16* lkd = lds_k + (buf ^ 1) * 4096;
        u16* lvd = lds_v + (buf ^ 1) * 4096;
        *(short8*)&lkd[sw0] = nk0;
        *(short8*)&lkd[sw1] = nk1;
        *(s16x4*)&lvd[vw0] = nv0.h[0];
        *(s16x4*)&lvd[vw1] = nv0.h[1];
        *(s16x4*)&lvd[vw2] = nv1.h[0];
        *(s16x4*)&lvd[vw3] = nv1.h[1];
    }

    // ---- epilogue: branchless cross-wk reduction + out-projection ----
    __syncthreads();                           // all frag reads done; smem reusable

    // per-wave l partials (uniform per lq after quad reduction)
    float lsum[4];
#pragma unroll
    for (int qt = 0; qt < 4; ++qt) {
        float l = (lp[qt][0] + lp[qt][1]) + (lp[qt][2] + lp[qt][3]);
        l += __shfl_xor(l, 16);
        l += __shfl_xor(l, 32);
        lsum[qt] = l;
    }

    float* red = (float*)smem;                 // 8 regions x 1024 f32 (32 KB)
    const int hq = (1 - wk) * 2;               // handed-off qt base (runtime addr math)
    const int kq = wk * 2;                     // kept qt base
    const int off = lq * 64 + quad * 4;

    // hand off: register SELECTS (literal ot indices -> v_cndmask, no scratch)
#pragma unroll
    for (int ct = 0; ct < 4; ++ct) {
        *(f32x4*)&red[(wq * 4 + hq + 0) * 1024 + off + ct * 16] =
            wk ? ot[0][ct] : ot[2][ct];
        *(f32x4*)&red[(wq * 4 + hq + 1) * 1024 + off + ct * 16] =
            wk ? ot[1][ct] : ot[3][ct];
    }
    lpbuf[wq * 4 + hq + 0][lq] = wk ? lsum[0] : lsum[2];
    lpbuf[wq * 4 + hq + 1][lq] = wk ? lsum[1] : lsum[3];

    // kept halves into fresh registers (selects, literal indices, NO pointers)
    f32x4 kp0[4], kp1[4];
#pragma unroll
    for (int ct = 0; ct < 4; ++ct) {
        kp0[ct] = wk ? ot[2][ct] : ot[0][ct];
        kp1[ct] = wk ? ot[3][ct] : ot[1][ct];
    }
    const float lk0 = wk ? lsum[2] : lsum[0];
    const float lk1 = wk ? lsum[3] : lsum[1];

    __syncthreads();

    bf16x8 wf[2][4];
#pragma unroll
    for (int kc = 0; kc < 2; ++kc)
#pragma unroll
        for (int nt = 0; nt < 4; ++nt)
            wf[kc][nt] = ldw8(ow + (nt * 16 + lq) * 64 + kc * 32 + quad * 8);
    float bias[4];
#pragma unroll
    for (int nt = 0; nt < 4; ++nt) bias[nt] = ob[nt * 16 + lq];

// out-project one kept half. KP is an ARRAY NAME (kp0/kp1) -> every access
// is a literal-indexed register; T is a literal.
#define EPI_OUT(KP, LSELF, T) do {                                            \
    _Pragma("unroll")                                                         \
    for (int ct = 0; ct < 4; ++ct)                                            \
        KP[ct] += *(const f32x4*)&red[(wq * 4 + kq + T) * 1024 + off + ct * 16]; \
    const float l_   = (LSELF) + lpbuf[wq * 4 + kq + T][lq];                  \
    const float inv_ = 1.0f / l_;                                             \
    u16* po_ = lds_p[w * 2 + T];                                              \
    _Pragma("unroll")                                                         \
    for (int ct = 0; ct < 4; ++ct) {                                          \
        uint2 pv_;                                                            \
        pv_.x = pkbf(KP[ct][0] * inv_, KP[ct][1] * inv_);                     \
        pv_.y = pkbf(KP[ct][2] * inv_, KP[ct][3] * inv_);                     \
        *(uint2*)&po_[lq * 64 + (((ct * 2 + (quad >> 1)) ^ lsw) << 3)         \
                      + (quad & 1) * 4] = pv_;                                \
    }                                                                         \
    bf16x8 oa0_ = *(const bf16x8*)&po_[lq * 64 + (((0 + quad) ^ lsw) << 3)];  \
    bf16x8 oa1_ = *(const bf16x8*)&po_[lq * 64 + (((4 + quad) ^ lsw) << 3)];  \
    f32x4 a0_ = (f32x4){bias[0], bias[0], bias[0], bias[0]};                  \
    f32x4 a1_ = (f32x4){bias[1], bias[1], bias[1], bias[1]};                  \
    f32x4 a2_ = (f32x4){bias[2], bias[2], bias[2], bias[2]};                  \
    f32x4 a3_ = (f32x4){bias[3], bias[3], bias[3], bias[3]};                  \
    a0_ = __builtin_amdgcn_mfma_f32_16x16x32_bf16(oa0_, wf[0][0], a0_, 0, 0, 0); \
    a0_ = __builtin_amdgcn_mfma_f32_16x16x32_bf16(oa1_, wf[1][0], a0_, 0, 0, 0); \
    a1_ = __builtin_amdgcn_mfma_f32_16x16x32_bf16(oa0_, wf[0][1], a1_, 0, 0, 0); \
    a1_ = __builtin_amdgcn_mfma_f32_16x16x32_bf16(oa1_, wf[1][1], a1_, 0, 0, 0); \
    a2_ = __builtin_amdgcn_mfma_f32_16x16x32_bf16(oa0_, wf[0][2], a2_, 0, 0, 0); \
    a2_ = __builtin_amdgcn_mfma_f32_16x16x32_bf16(oa1_, wf[1][2], a2_, 0, 0, 0); \
    a3_ = __builtin_amdgcn_mfma_f32_16x16x32_bf16(oa0_, wf[0][3], a3_, 0, 0, 0); \
    a3_ = __builtin_amdgcn_mfma_f32_16x16x32_bf16(oa1_, wf[1][3], a3_, 0, 0, 0); \
    float* d0_ = out + ((size_t)(b * CC +  0 + lq)) * SS + q0 + wq * 64 + (kq + T) * 16 + quad * 4; \
    float* d1_ = out + ((size_t)(b * CC + 16 + lq)) * SS + q0 + wq * 64 + (kq + T) * 16 + quad * 4; \
    float* d2_ = out + ((size_t)(b * CC + 32 + lq)) * SS + q0 + wq * 64 + (kq + T) * 16 + quad * 4; \
    float* d3_ = out + ((size_t)(b * CC + 48 + lq)) * SS + q0 + wq * 64 + (kq + T) * 16 + quad * 4; \
    *(f32x4*)d0_ = a0_;                                                       \
    *(f32x4*)d1_ = a1_;                                                       \
    *(f32x4*)d2_ = a2_;                                                       \
    *(f32x4*)d3_ = a3_;                                                       \
} while (0)

    EPI_OUT(kp0, lk0, 0);
    EPI_OUT(kp1, lk1, 1);
#undef EPI_OUT
}

// ---------------------------------------------------------------------------
extern "C" void kernel_launch(void* const* d_in, const int* in_sizes, int n_in,
                              void* d_out, int out_size, void* d_ws, size_t ws_size,
                              hipStream_t stream)
{
    const float* x  = (const float*)d_in[0];
    const float* qw = (const float*)d_in[1];
    const float* qb = (const float*)d_in[2];
    const float* kw = (const float*)d_in[3];
    const float* kb = (const float*)d_in[4];
    const float* vw = (const float*)d_in[5];
    const float* vb = (const float*)d_in[6];
    const float* ow = (const float*)d_in[7];
    const float* ob = (const float*)d_in[8];
    float* out = (float*)d_out;

    const size_t T = (size_t)BB * SS * CC;
    u16* Q  = (u16*)d_ws;
    u16* K  = Q + T;
    u16* VT = K + T;

    qkv_kernel<<<dim3(BB * 64), dim3(256), 0, stream>>>(x, qw, qb, kw, kb, vw, vb, Q, K, VT);
    flash_kernel<<<dim3(BB * 32), dim3(256), 0, stream>>>(Q, K, VT, ow, ob, out);
}

// Round 9
// 160.410 us; speedup vs baseline: 2.3809x; 2.3809x over previous
//
#include <hip/hip_runtime.h>
#include <stdint.h>

#define SS 4096     // tokens per batch (H*W)
#define CC 64       // channels
#define BB 16       // batch

typedef unsigned short u16;
typedef __attribute__((ext_vector_type(8))) __bf16 bf16x8;
typedef __attribute__((ext_vector_type(8))) short short8;
typedef __attribute__((ext_vector_type(4))) short s16x4;
typedef __attribute__((ext_vector_type(4))) float f32x4;

// pack two f32 -> two bf16 in one u32 (low = a, high = b), round-half-up
__device__ __forceinline__ uint32_t pkbf(float a, float b) {
    uint32_t ua = __float_as_uint(a) + 0x8000u;
    uint32_t ub = __float_as_uint(b) + 0x8000u;
    return __builtin_amdgcn_perm(ub, ua, 0x07060302u);
}

// hardware packed f32x2 -> bf16x2 (RNE), low = a, high = b
__device__ __forceinline__ uint32_t cvtpk(float a, float b) {
    uint32_t r;
    asm("v_cvt_pk_bf16_f32 %0, %1, %2" : "=v"(r) : "v"(a), "v"(b));
    return r;
}

// load 8 consecutive fp32 -> bf16x8 fragment (L2-hot, once/block)
__device__ __forceinline__ bf16x8 ldw8(const float* p) {
    f32x4 lo = *(const f32x4*)(p);
    f32x4 hi = *(const f32x4*)(p + 4);
    union { uint32_t u[4]; bf16x8 v; } r;
    r.u[0] = pkbf(lo[0], lo[1]);
    r.u[1] = pkbf(lo[2], lo[3]);
    r.u[2] = pkbf(hi[0], hi[1]);
    r.u[3] = pkbf(hi[2], hi[3]);
    return r.v;
}

// ---------------------------------------------------------------------------
// Kernel A: QKV projection — R2-verified version, unchanged.
// ---------------------------------------------------------------------------
__global__ __launch_bounds__(256, 4) void qkv_kernel(
    const float* __restrict__ x,
    const float* __restrict__ qw, const float* __restrict__ qb,
    const float* __restrict__ kw, const float* __restrict__ kb,
    const float* __restrict__ vw, const float* __restrict__ vb,
    u16* __restrict__ Q, u16* __restrict__ K, u16* __restrict__ VT)
{
    const int b    = blockIdx.x & 15;          // batch-major for XCD locality
    const int s0   = (blockIdx.x >> 4) << 6;   // 64 s per block
    const int tid  = threadIdx.x;
    const int w    = tid >> 6;
    const int lane = tid & 63;
    const int lq   = lane & 15;
    const int quad = lane >> 4;

    __shared__ u16 wt[3][64 * 72];             // weights bf16 [o][c]
    __shared__ u16 xt[64 * 72];                // x-tile transposed [s][c]; later bounce

    // ---- stage weights bf16 (coalesced 512-B reads, conflict-spread writes) ----
    for (int m = 0; m < 3; ++m) {
        const float* wsrc = (m == 0) ? qw : ((m == 1) ? kw : vw);
#pragma unroll
        for (int i = 0; i < 8; ++i) {
            int p  = tid + (i << 8);           // pair index 0..2047
            int o  = p >> 5;
            int cp = p & 31;
            const float* wp = wsrc + o * 64 + cp * 2;
            ((uint32_t*)&wt[m][o * 72])[cp] = pkbf(wp[0], wp[1]);
        }
    }
    // ---- stage x-tile transposed (reads: 64 consecutive s = 256 B/instr) ----
    {
        const int sl = tid & 63;
        const int g  = tid >> 6;
        const float* xp = x + (size_t)b * CC * SS + s0 + sl;
#pragma unroll
        for (int i = 0; i < 8; ++i) {
            int p = g + (i << 2);              // c-pair 0..31
            float f0 = xp[(size_t)(2 * p) * SS];
            float f1 = xp[(size_t)(2 * p + 1) * SS];
            ((uint32_t*)&xt[sl * 72])[p] = pkbf(f0, f1);
        }
    }
    __syncthreads();

    // A-frags for my 16 s-rows
    bf16x8 a0 = *(const bf16x8*)&xt[(w * 16 + lq) * 72 + quad * 8];
    bf16x8 a1 = *(const bf16x8*)&xt[(w * 16 + lq) * 72 + 32 + quad * 8];
    __syncthreads();                           // xt dead -> reuse as bounce

    u16* bb = xt + w * (16 * 72);              // per-wave bounce

    const float QSCALE = 0.125f * 1.44269504088896340736f;

    for (int m = 0; m < 3; ++m) {
        const float* bsrc = (m == 0) ? qb : ((m == 1) ? kb : vb);
        bf16x8 bfr[2][4];
#pragma unroll
        for (int kc = 0; kc < 2; ++kc)
#pragma unroll
            for (int nt = 0; nt < 4; ++nt)
                bfr[kc][nt] = *(const bf16x8*)&wt[m][(nt * 16 + lq) * 72 + kc * 32 + quad * 8];

        f32x4 acc[4];
#pragma unroll
        for (int nt = 0; nt < 4; ++nt) {
            float bv = bsrc[nt * 16 + lq];
            acc[nt] = (f32x4){bv, bv, bv, bv};
        }
#pragma unroll
        for (int nt = 0; nt < 4; ++nt) {
            acc[nt] = __builtin_amdgcn_mfma_f32_16x16x32_bf16(a0, bfr[0][nt], acc[nt], 0, 0, 0);
            acc[nt] = __builtin_amdgcn_mfma_f32_16x16x32_bf16(a1, bfr[1][nt], acc[nt], 0, 0, 0);
        }

        if (m == 2) {
            // VT[b][c][s]: lane has col c, 4 consecutive s -> 8B store
#pragma unroll
            for (int nt = 0; nt < 4; ++nt) {
                int c = nt * 16 + lq;
                uint2 pv;
                pv.x = pkbf(acc[nt][0], acc[nt][1]);
                pv.y = pkbf(acc[nt][2], acc[nt][3]);
                *(uint2*)(VT + ((size_t)(b * CC + c)) * SS + s0 + w * 16 + quad * 4) = pv;
            }
        } else {
            const float scl = (m == 0) ? QSCALE : 1.0f;
#pragma unroll
            for (int nt = 0; nt < 4; ++nt)
#pragma unroll
                for (int r = 0; r < 4; ++r)
                    bb[(quad * 4 + r) * 72 + nt * 16 + lq] =
                        (u16)((__float_as_uint(acc[nt][r] * scl) + 0x8000u) >> 16);

            const int row = lane >> 2;
            const int ch  = (lane & 3) << 4;
            short8 v0 = *(const short8*)&bb[row * 72 + ch];       // wave-private RAW
            short8 v1 = *(const short8*)&bb[row * 72 + ch + 8];
            u16* dst = ((m == 0) ? Q : K) + ((size_t)(b * SS + s0 + w * 16 + row)) * CC + ch;
            *(short8*)dst = v0;
            *(short8*)(dst + 8) = v1;
        }
    }
}

// ---------------------------------------------------------------------------
// Kernel B: flash attention + fused out-projection.
// V14 = R2-verified structure (zero-LDS P via permuted V slot order, K+V
// LDS double-buffer, 2 q-groups/wave, setprio on MFMA clusters) + two
// individually-verified micro-opts:
//   (a) sa zero-init folded into the first MFMA's C operand (ZV — R4).
//   (b) softmax P-pack via v_cvt_pk_bf16_f32 (1 op vs 3 — R5/R7/R8).
// The 2x2 wave-split line (R5-R8) is closed: compiler demotes the enlarged
// accumulator state to scratch (~1.9GB WRITE) regardless of source form.
// ---------------------------------------------------------------------------
__global__ __launch_bounds__(256, 2) void flash_kernel(
    const u16* __restrict__ Q, const u16* __restrict__ K,
    const u16* __restrict__ Vt, const float* __restrict__ ow,
    const float* __restrict__ ob, float* __restrict__ out)
{
    const int b    = blockIdx.x & 15;          // batch-major: XCD gets 2 batches
    const int q0   = (blockIdx.x >> 4) << 7;   // 128 q per block
    const int tid  = threadIdx.x;
    const int w    = tid >> 6;
    const int lane = tid & 63;
    const int lq   = lane & 15;
    const int quad = lane >> 4;

    __shared__ u16 lds_k[2][64 * 64];          // K tile [key][c], chunk-XOR swizzled
    __shared__ u16 lds_v[2][64 * 64];          // V^T tile [c][slot], key-permuted + swizzled
    __shared__ u16 lds_p[8][16 * 64];          // epilogue O bounce only

    // Q B-frags for both groups
    bf16x8 qf[2][2];
#pragma unroll
    for (int g = 0; g < 2; ++g) {
        const u16* qp = Q + ((size_t)(b * SS + q0 + g * 64 + w * 16 + lq)) * CC + quad * 8;
        qf[g][0] = *(const bf16x8*)(qp);
        qf[g][1] = *(const bf16x8*)(qp + 32);
    }

    f32x4 ot[2][4];
#pragma unroll
    for (int g = 0; g < 2; ++g)
#pragma unroll
        for (int ct = 0; ct < 4; ++ct) ot[g][ct] = (f32x4){0.f, 0.f, 0.f, 0.f};
    float lp[2][4] = {{0.f, 0.f, 0.f, 0.f}, {0.f, 0.f, 0.f, 0.f}};

    const f32x4 ZV = (f32x4){0.f, 0.f, 0.f, 0.f};   // loop-invariant MFMA C=0

    // staging: thread covers row srow, 16B K-chunks 2a, 2a+1 (XOR-swizzled);
    // V as 4x 8B pieces at permuted slots.
    const int srow = tid >> 2;
    const int a    = tid & 3;
    const u16* kg = K + ((size_t)(b * SS + srow)) * CC + a * 16;
    const u16* vg = Vt + ((size_t)(b * CC + srow)) * SS + a * 16;
    const int ssw = srow & 7;
    const int sw0 = srow * 64 + ((((a << 1)    ) ^ ssw) << 3);
    const int sw1 = srow * 64 + ((((a << 1) | 1) ^ ssw) << 3);
    // V permuted-slot write offsets: this thread holds (kc = a>>1, u = a&1),
    // pieces q=0..3 of 4 keys each -> slot chunk 4kc+q, intra-chunk offset 4u.
    const int kcs = (a >> 1) << 2;
    const int us  = (a & 1) << 2;
    const int vw0 = srow * 64 + (((kcs + 0) ^ ssw) << 3) + us;
    const int vw1 = srow * 64 + (((kcs + 1) ^ ssw) << 3) + us;
    const int vw2 = srow * 64 + (((kcs + 2) ^ ssw) << 3) + us;
    const int vw3 = srow * 64 + (((kcs + 3) ^ ssw) << 3) + us;

    {   // prologue: tile 0 -> buf 0
        short8 k0 = *(const short8*)(kg);
        short8 k1 = *(const short8*)(kg + 8);
        union { short8 v; s16x4 h[2]; } v0, v1;
        v0.v = *(const short8*)(vg);
        v1.v = *(const short8*)(vg + 8);
        *(short8*)&lds_k[0][sw0] = k0;
        *(short8*)&lds_k[0][sw1] = k1;
        *(s16x4*)&lds_v[0][vw0] = v0.h[0];
        *(s16x4*)&lds_v[0][vw1] = v0.h[1];
        *(s16x4*)&lds_v[0][vw2] = v1.h[0];
        *(s16x4*)&lds_v[0][vw3] = v1.h[1];
    }

    const int lsw = lq & 7;
    u16* pw0 = lds_p[(w << 1)];
    u16* pw1 = lds_p[(w << 1) | 1];

    for (int kt = 0; kt < 64; ++kt) {
        __syncthreads();
        const int buf = kt & 1;

        // prefetch tile kt+1 (consumed at end of body)
        const int ktn = (kt + 1) & 63;
        const u16* kgn = kg + (size_t)ktn * (64 * CC);
        const u16* vgn = vg + ktn * 64;
        short8 nk0 = *(const short8*)(kgn);
        short8 nk1 = *(const short8*)(kgn + 8);
        union { short8 v; s16x4 h[2]; } nv0, nv1;
        nv0.v = *(const short8*)(vgn);
        nv1.v = *(const short8*)(vgn + 8);

        // K frags loaded ONCE, feed both q-groups
        bf16x8 kf[2][4];
#pragma unroll
        for (int kc = 0; kc < 2; ++kc)
#pragma unroll
            for (int mt = 0; mt < 4; ++mt)
                kf[kc][mt] = *(const bf16x8*)
                    &lds_k[buf][(mt * 16 + lq) * 64 + (((kc << 2) + quad) ^ lsw) * 8];

        // S^T = K * Q^T for both groups (C=0 folded via ZV)
        f32x4 sa[2][4];
        __builtin_amdgcn_s_setprio(1);
#pragma unroll
        for (int g = 0; g < 2; ++g)
#pragma unroll
            for (int mt = 0; mt < 4; ++mt) {
                sa[g][mt] = __builtin_amdgcn_mfma_f32_16x16x32_bf16(
                    kf[0][mt], qf[g][0], ZV, 0, 0, 0);
                sa[g][mt] = __builtin_amdgcn_mfma_f32_16x16x32_bf16(
                    kf[1][mt], qf[g][1], sa[g][mt], 0, 0, 0);
            }
        __builtin_amdgcn_s_setprio(0);

        // V frags loaded ONCE (hoisted above softmax for latency cover);
        // same verified b128 pattern — elements are permuted-slot order.
        bf16x8 vf[2][4];
#pragma unroll
        for (int kc = 0; kc < 2; ++kc)
#pragma unroll
            for (int ct = 0; ct < 4; ++ct)
                vf[kc][ct] = *(const bf16x8*)
                    &lds_v[buf][(ct * 16 + lq) * 64 + (((kc << 2) + quad) ^ lsw) * 8];

        // softmax (fixed max): p = exp2(s); pack straight into PV B-frags.
        // pf[kc] element j: j<4 -> p[mt=2kc][r=j], j>=4 -> p[mt=2kc+1][r=j-4],
        // matching the permuted V slot order. Zero LDS, zero shuffles.
#pragma unroll
        for (int g = 0; g < 2; ++g) {
            union { uint32_t u[4]; bf16x8 v; } pf[2];
#pragma unroll
            for (int mt = 0; mt < 4; ++mt) {
                float p0 = __builtin_amdgcn_exp2f(sa[g][mt][0]);
                float p1 = __builtin_amdgcn_exp2f(sa[g][mt][1]);
                float p2 = __builtin_amdgcn_exp2f(sa[g][mt][2]);
                float p3 = __builtin_amdgcn_exp2f(sa[g][mt][3]);
                lp[g][0] += p0; lp[g][1] += p1; lp[g][2] += p2; lp[g][3] += p3;
                pf[mt >> 1].u[(mt & 1) * 2 + 0] = cvtpk(p0, p1);
                pf[mt >> 1].u[(mt & 1) * 2 + 1] = cvtpk(p2, p3);
            }
            // O^T += V^T * P^T
            __builtin_amdgcn_s_setprio(1);
#pragma unroll
            for (int kc = 0; kc < 2; ++kc)
#pragma unroll
                for (int ct = 0; ct < 4; ++ct)
                    ot[g][ct] = __builtin_amdgcn_mfma_f32_16x16x32_bf16(
                        vf[kc][ct], pf[kc].v, ot[g][ct], 0, 0, 0);
            __builtin_amdgcn_s_setprio(0);
        }

        // stage prefetched tile into other buffer
        u16* lkd = lds_k[buf ^ 1];
        u16* lvd = lds_v[buf ^ 1];
        *(short8*)&lkd[sw0] = nk0;
        *(short8*)&lkd[sw1] = nk1;
        *(s16x4*)&lvd[vw0] = nv0.h[0];
        *(s16x4*)&lvd[vw1] = nv0.h[1];
        *(s16x4*)&lvd[vw2] = nv1.h[0];
        *(s16x4*)&lvd[vw3] = nv1.h[1];
    }

    // ---- fused out-projection epilogue ----
    bf16x8 wf[2][4];
#pragma unroll
    for (int kc = 0; kc < 2; ++kc)
#pragma unroll
        for (int nt = 0; nt < 4; ++nt)
            wf[kc][nt] = ldw8(ow + (nt * 16 + lq) * 64 + kc * 32 + quad * 8);
    float bias[4];
#pragma unroll
    for (int nt = 0; nt < 4; ++nt) bias[nt] = ob[nt * 16 + lq];

#pragma unroll
    for (int g = 0; g < 2; ++g) {
        float l = (lp[g][0] + lp[g][1]) + (lp[g][2] + lp[g][3]);
        l += __shfl_xor(l, 16);
        l += __shfl_xor(l, 32);
        const float inv = 1.0f / l;

        u16* po = g ? pw1 : pw0;
#pragma unroll
        for (int ct = 0; ct < 4; ++ct) {
            uint2 pv;
            pv.x = pkbf(ot[g][ct][0] * inv, ot[g][ct][1] * inv);
            pv.y = pkbf(ot[g][ct][2] * inv, ot[g][ct][3] * inv);
            *(uint2*)&po[lq * 64 + (((ct * 2 + (quad >> 1)) ^ lsw) << 3) + (quad & 1) * 4] = pv;
        }
        bf16x8 oa0 = *(const bf16x8*)&po[lq * 64 + (((0 * 4 + quad) ^ lsw) << 3)];
        bf16x8 oa1 = *(const bf16x8*)&po[lq * 64 + (((1 * 4 + quad) ^ lsw) << 3)];

        f32x4 acc[4];
#pragma unroll
        for (int nt = 0; nt < 4; ++nt)
            acc[nt] = (f32x4){bias[nt], bias[nt], bias[nt], bias[nt]};
#pragma unroll
        for (int nt = 0; nt < 4; ++nt) {
            acc[nt] = __builtin_amdgcn_mfma_f32_16x16x32_bf16(oa0, wf[0][nt], acc[nt], 0, 0, 0);
            acc[nt] = __builtin_amdgcn_mfma_f32_16x16x32_bf16(oa1, wf[1][nt], acc[nt], 0, 0, 0);
        }
#pragma unroll
        for (int nt = 0; nt < 4; ++nt) {
            float* dst = out + ((size_t)(b * CC + nt * 16 + lq)) * SS
                       + q0 + g * 64 + w * 16 + quad * 4;
            *(f32x4*)dst = acc[nt];
        }
    }
}

// ---------------------------------------------------------------------------
extern "C" void kernel_launch(void* const* d_in, const int* in_sizes, int n_in,
                              void* d_out, int out_size, void* d_ws, size_t ws_size,
                              hipStream_t stream)
{
    const float* x  = (const float*)d_in[0];
    const float* qw = (const float*)d_in[1];
    const float* qb = (const float*)d_in[2];
    const float* kw = (const float*)d_in[3];
    const float* kb = (const float*)d_in[4];
    const float* vw = (const float*)d_in[5];
    const float* vb = (const float*)d_in[6];
    const float* ow = (const float*)d_in[7];
    const float* ob = (const float*)d_in[8];
    float* out = (float*)d_out;

    const size_t T = (size_t)BB * SS * CC;
    u16* Q  = (u16*)d_ws;
    u16* K  = Q + T;
    u16* VT = K + T;

    qkv_kernel<<<dim3(BB * 64), dim3(256), 0, stream>>>(x, qw, qb, kw, kb, vw, vb, Q, K, VT);
    flash_kernel<<<dim3(BB * 32), dim3(256), 0, stream>>>(Q, K, VT, ow, ob, out);
}